// Round 3
// baseline (173.559 us; speedup 1.0000x reference)
//
#include <hip/hip_runtime.h>
#include <hip/hip_bf16.h>
#include <stdint.h>

// Problem constants
#define BB   2
#define CIN  32
#define COUT 16
#define DD   48
#define HIN  64
#define WIN  128
#define H2   128   // 2*HIN
#define W2   256   // 2*WIN
#define PLANE_WORDS (H2 * W2)   // 32768 sign-words per (b,d) plane

// ---------------------------------------------------------------------------
// prep: pack weight signs (bit ci of bw[tap*16+co] = sign(W[co][ci][tap])>0)
// and fold alpha into BN scale/shift.
// ---------------------------------------------------------------------------
__global__ __launch_bounds__(512) void ibc3d_prep(
    const float* __restrict__ wgt, const float* __restrict__ gamma,
    const float* __restrict__ beta, const float* __restrict__ rmean,
    const float* __restrict__ rvar, uint32_t* __restrict__ bw,
    float* __restrict__ scale, float* __restrict__ shift)
{
    int t = threadIdx.x;
    if (t < 27 * 16) {
        int tap = t >> 4, co = t & 15;
        uint32_t word = 0;
        for (int ci = 0; ci < CIN; ++ci) {
            float v = wgt[(co * CIN + ci) * 27 + tap];
            word |= (v > 0.0f ? 1u : 0u) << ci;
        }
        bw[t] = word;
    } else if (t < 27 * 16 + 16) {
        int co = t - 27 * 16;
        double s = 0.0;
        for (int i = 0; i < CIN * 27; ++i)
            s += fabs((double)wgt[co * CIN * 27 + i]);
        float alpha = (float)(s / (double)(CIN * 27));
        float inv = gamma[co] / sqrtf(rvar[co] + 1e-5f);
        scale[co] = alpha * inv;
        shift[co] = beta[co] - rmean[co] * inv;
    }
}

// ---------------------------------------------------------------------------
// pack: bilinear 2x upsample in H,W (depth identity), half-pixel centers,
// edge clamp (== jax renorm at borders), fp64 interpolation, sign-pack the
// 32 input channels into one uint32.
// ---------------------------------------------------------------------------
__device__ __forceinline__ uint32_t pack_word(const float* __restrict__ x,
                                              int b, int d, int h2, int w2)
{
    int m = h2 >> 1, dh = h2 & 1;
    int n = w2 >> 1, dwp = w2 & 1;
    int rA = m + dh - 1;
    int rB = rA + 1;
    double wA = dh ? 0.75 : 0.25;
    double wB = 1.0 - wA;
    rA = rA < 0 ? 0 : rA;
    rB = rB > (HIN - 1) ? (HIN - 1) : rB;
    int cA = n + dwp - 1;
    int cB = cA + 1;
    double wC = dwp ? 0.75 : 0.25;
    double wD = 1.0 - wC;
    cA = cA < 0 ? 0 : cA;
    cB = cB > (WIN - 1) ? (WIN - 1) : cB;

    const float* xp = x + ((size_t)b * CIN * DD + d) * (HIN * WIN);
    int oA = rA * WIN, oB = rB * WIN;
    uint32_t word = 0;
    for (int ci = 0; ci < CIN; ++ci) {
        const float* xc = xp + (size_t)ci * (DD * HIN * WIN);
        float a0 = xc[oA + cA], a1 = xc[oA + cB];
        float b0 = xc[oB + cA], b1 = xc[oB + cB];
        double t0 = wA * (double)a0 + wB * (double)b0;
        double t1 = wA * (double)a1 + wB * (double)b1;
        double v  = wC * t0 + wD * t1;
        word |= (v >= 0.0 ? 1u : 0u) << ci;
    }
    return word;
}

__global__ __launch_bounds__(256) void ibc3d_pack2(
    const float* __restrict__ x, uint32_t* __restrict__ bx,
    int b_start, int nplanes)
{
    int idx = blockIdx.x * 256 + threadIdx.x;   // [0, nplanes*32768)
    if (idx >= nplanes * PLANE_WORDS) return;
    int w2 = idx & (W2 - 1);
    int h2 = (idx >> 8) & (H2 - 1);
    int rl = idx >> 15;                         // local plane
    int d  = rl % DD;
    int b  = b_start + rl / DD;
    bx[idx] = pack_word(x, b, d, h2, w2);
}

// ---------------------------------------------------------------------------
// conv2: one thread = one (plane, h2, w2), all 16 co.
// Per valid tap: sum_ci sx*sw = 32 - 2*popc(bx ^ bw); padding (xb=0) taps
// contribute nothing and are skipped via nv.
// ---------------------------------------------------------------------------
__global__ __launch_bounds__(256) void ibc3d_conv2(
    const uint32_t* __restrict__ bx, const uint32_t* __restrict__ bwg,
    const float* __restrict__ scaleg, const float* __restrict__ shiftg,
    float* __restrict__ out, int b_start)
{
    __shared__ uint32_t sbw[27 * 16];
    __shared__ float sscale[16];
    __shared__ float sshift[16];
    int tid = threadIdx.x;
    for (int i = tid; i < 27 * 16; i += 256) sbw[i] = bwg[i];
    if (tid < 16) { sscale[tid] = scaleg[tid]; sshift[tid] = shiftg[tid]; }
    __syncthreads();

    int bid   = blockIdx.x;          // plane*128 + h2
    int h2    = bid & (H2 - 1);
    int plane = bid >> 7;            // [0, nb*48)
    int d     = plane % DD;
    int b     = b_start + plane / DD;
    int w2    = tid;

    int acc[16];
#pragma unroll
    for (int c = 0; c < 16; ++c) acc[c] = 0;
    int nv = 0;

    for (int kd = 0; kd < 3; ++kd) {
        int dd = d + kd - 1;
        if (dd < 0 || dd >= DD) continue;                 // wave-uniform
        const uint32_t* bxp = bx + (size_t)(plane + kd - 1) * PLANE_WORDS;
        for (int kh = 0; kh < 3; ++kh) {
            int hh = h2 + kh - 1;
            if (hh < 0 || hh >= H2) continue;             // wave-uniform
            for (int kw = 0; kw < 3; ++kw) {
                int ww = w2 + kw - 1;
                if (ww < 0 || ww >= W2) continue;         // per-lane (edges)
                uint32_t word = bxp[hh * W2 + ww];
                nv += 1;
                int tap = kd * 9 + kh * 3 + kw;
#pragma unroll
                for (int co = 0; co < 16; ++co)
                    acc[co] += __popc(word ^ sbw[tap * 16 + co]);
            }
        }
    }

    float base = 32.0f * (float)nv;
#pragma unroll
    for (int co = 0; co < 16; ++co) {
        float y = (base - 2.0f * (float)acc[co]) * sscale[co] + sshift[co];
        y = y > 0.0f ? y : 0.0f;
        size_t oidx = (((size_t)(b * COUT + co) * DD + d) * H2 + h2) * W2 + w2;
        out[oidx] = y;
    }
}

// ---------------------------------------------------------------------------
// fused: zero-scratch fallback. Block = (b, d, hq of 8 output rows).
// Packs its own 3x10x258 sign-word window into LDS, recomputes bw/scale
// in LDS, then does the popcount conv entirely from LDS.
// ---------------------------------------------------------------------------
__global__ __launch_bounds__(256) void ibc3d_fused(
    const float* __restrict__ x, const float* __restrict__ wgt,
    const float* __restrict__ gamma, const float* __restrict__ beta,
    const float* __restrict__ rmean, const float* __restrict__ rvar,
    float* __restrict__ out)
{
    __shared__ uint32_t sbw[27 * 16];
    __shared__ float sscale[16];
    __shared__ float sshift[16];
    __shared__ uint32_t sw[3][10][264];   // [kd][row][col+1], rows h2base-1..+8

    int tid = threadIdx.x;
    for (int t = tid; t < 27 * 16; t += 256) {
        int tap = t >> 4, co = t & 15;
        uint32_t word = 0;
        for (int ci = 0; ci < CIN; ++ci) {
            float v = wgt[(co * CIN + ci) * 27 + tap];
            word |= (v > 0.0f ? 1u : 0u) << ci;
        }
        sbw[t] = word;
    }
    if (tid < 16) {
        int co = tid;
        double s = 0.0;
        for (int i = 0; i < CIN * 27; ++i)
            s += fabs((double)wgt[co * CIN * 27 + i]);
        float alpha = (float)(s / (double)(CIN * 27));
        float inv = gamma[co] / sqrtf(rvar[co] + 1e-5f);
        sscale[co] = alpha * inv;
        sshift[co] = beta[co] - rmean[co] * inv;
    }

    int bid = blockIdx.x;          // (b*48 + d)*16 + hq
    int hq  = bid & 15;
    int r   = bid >> 4;
    int b   = r / DD;
    int d   = r % DD;
    int h2base = hq * 8;

    for (int i = tid; i < 3 * 10 * 258; i += 256) {
        int kd  = i / 2580;
        int rem = i - kd * 2580;
        int ri  = rem / 258;
        int ciw = rem - ri * 258;      // col index; ww = ciw-1
        int dd = d + kd - 1;
        int h2 = h2base - 1 + ri;
        int w2 = ciw - 1;
        uint32_t word = 0;
        if (dd >= 0 && dd < DD && h2 >= 0 && h2 < H2 && w2 >= 0 && w2 < W2)
            word = pack_word(x, b, dd, h2, w2);
        sw[kd][ri][ciw] = word;
    }
    __syncthreads();

    int w2 = tid;
    for (int p = 0; p < 8; ++p) {
        int h2 = h2base + p;
        int acc[16];
#pragma unroll
        for (int c = 0; c < 16; ++c) acc[c] = 0;
        int nv = 0;
        for (int kd = 0; kd < 3; ++kd) {
            int dd = d + kd - 1;
            if (dd < 0 || dd >= DD) continue;
            for (int kh = 0; kh < 3; ++kh) {
                int hh = h2 + kh - 1;
                if (hh < 0 || hh >= H2) continue;
                for (int kw = 0; kw < 3; ++kw) {
                    int ww = w2 + kw - 1;
                    if (ww < 0 || ww >= W2) continue;
                    uint32_t word = sw[kd][p + kh][w2 + kw];
                    nv += 1;
                    int tap = kd * 9 + kh * 3 + kw;
#pragma unroll
                    for (int co = 0; co < 16; ++co)
                        acc[co] += __popc(word ^ sbw[tap * 16 + co]);
                }
            }
        }
        float base = 32.0f * (float)nv;
#pragma unroll
        for (int co = 0; co < 16; ++co) {
            float y = (base - 2.0f * (float)acc[co]) * sscale[co] + sshift[co];
            y = y > 0.0f ? y : 0.0f;
            size_t oidx = (((size_t)(b * COUT + co) * DD + d) * H2 + h2) * W2 + w2;
            out[oidx] = y;
        }
    }
}

extern "C" void kernel_launch(void* const* d_in, const int* in_sizes, int n_in,
                              void* d_out, int out_size, void* d_ws, size_t ws_size,
                              hipStream_t stream)
{
    (void)in_sizes; (void)n_in; (void)out_size;
    const float* x     = (const float*)d_in[0];
    const float* wgt   = (const float*)d_in[1];
    const float* gamma = (const float*)d_in[2];
    const float* beta  = (const float*)d_in[3];
    const float* rmean = (const float*)d_in[4];
    const float* rvar  = (const float*)d_in[5];
    float* out = (float*)d_out;

    const size_t HDR = 4096;
    const size_t bx_full = (size_t)BB * DD * PLANE_WORDS * 4;  // 12.58 MB
    const size_t bx_half = (size_t)DD * PLANE_WORDS * 4;       //  6.29 MB

    if (d_ws != nullptr && ws_size >= HDR + bx_full) {
        uint8_t* ws = (uint8_t*)d_ws;
        uint32_t* bw    = (uint32_t*)ws;
        float*    scale = (float*)(ws + 2048);
        float*    shift = (float*)(ws + 2112);
        uint32_t* bx    = (uint32_t*)(ws + HDR);
        ibc3d_prep<<<1, 512, 0, stream>>>(wgt, gamma, beta, rmean, rvar, bw, scale, shift);
        int nplanes = BB * DD;                      // 96
        ibc3d_pack2<<<nplanes * (PLANE_WORDS / 256), 256, 0, stream>>>(x, bx, 0, nplanes);
        ibc3d_conv2<<<nplanes * H2, 256, 0, stream>>>(bx, bw, scale, shift, out, 0);
    } else if (d_ws != nullptr && ws_size >= HDR + bx_half) {
        uint8_t* ws = (uint8_t*)d_ws;
        uint32_t* bw    = (uint32_t*)ws;
        float*    scale = (float*)(ws + 2048);
        float*    shift = (float*)(ws + 2112);
        uint32_t* bx    = (uint32_t*)(ws + HDR);
        ibc3d_prep<<<1, 512, 0, stream>>>(wgt, gamma, beta, rmean, rvar, bw, scale, shift);
        for (int b = 0; b < BB; ++b) {              // stream serializes pack/conv pairs
            ibc3d_pack2<<<DD * (PLANE_WORDS / 256), 256, 0, stream>>>(x, bx, b, DD);
            ibc3d_conv2<<<DD * H2, 256, 0, stream>>>(bx, bw, scale, shift, out, b);
        }
    } else {
        ibc3d_fused<<<BB * DD * (H2 / 8), 256, 0, stream>>>(
            x, wgt, gamma, beta, rmean, rvar, out);
    }
}

// Round 4
// 162.085 us; speedup vs baseline: 1.0708x; 1.0708x over previous
//
#include <hip/hip_runtime.h>
#include <hip/hip_bf16.h>
#include <stdint.h>

// Problem constants
#define BB   2
#define CIN  32
#define COUT 16
#define DD   48
#define HIN  64
#define WIN  128
#define H2   128   // 2*HIN
#define W2   256   // 2*WIN
#define PLANE_WORDS (H2 * W2)   // 32768 sign-words per (b,d) plane

// ---------------------------------------------------------------------------
// prep: pack weight signs (bit ci of bw[tap*16+co] = sign(W[co][ci][tap])>0)
// and fold alpha into BN scale/shift.
// ---------------------------------------------------------------------------
__global__ __launch_bounds__(512) void ibc3d_prep(
    const float* __restrict__ wgt, const float* __restrict__ gamma,
    const float* __restrict__ beta, const float* __restrict__ rmean,
    const float* __restrict__ rvar, uint32_t* __restrict__ bw,
    float* __restrict__ scale, float* __restrict__ shift)
{
    int t = threadIdx.x;
    if (t < 27 * 16) {
        int tap = t >> 4, co = t & 15;
        uint32_t word = 0;
        for (int ci = 0; ci < CIN; ++ci) {
            float v = wgt[(co * CIN + ci) * 27 + tap];
            word |= (v > 0.0f ? 1u : 0u) << ci;
        }
        bw[t] = word;
    } else if (t < 27 * 16 + 16) {
        int co = t - 27 * 16;
        double s = 0.0;
        for (int i = 0; i < CIN * 27; ++i)
            s += fabs((double)wgt[co * CIN * 27 + i]);
        float alpha = (float)(s / (double)(CIN * 27));
        float inv = gamma[co] / sqrtf(rvar[co] + 1e-5f);
        scale[co] = alpha * inv;
        shift[co] = beta[co] - rmean[co] * inv;
    }
}

// ---------------------------------------------------------------------------
// pack_word (exact fp64 path, used by fused fallback only).
// ---------------------------------------------------------------------------
__device__ __forceinline__ uint32_t pack_word(const float* __restrict__ x,
                                              int b, int d, int h2, int w2)
{
    int m = h2 >> 1, dh = h2 & 1;
    int n = w2 >> 1, dwp = w2 & 1;
    int rA = m + dh - 1;
    int rB = rA + 1;
    double wA = dh ? 0.75 : 0.25;
    double wB = 1.0 - wA;
    rA = rA < 0 ? 0 : rA;
    rB = rB > (HIN - 1) ? (HIN - 1) : rB;
    int cA = n + dwp - 1;
    int cB = cA + 1;
    double wC = dwp ? 0.75 : 0.25;
    double wD = 1.0 - wC;
    cA = cA < 0 ? 0 : cA;
    cB = cB > (WIN - 1) ? (WIN - 1) : cB;

    const float* xp = x + ((size_t)b * CIN * DD + d) * (HIN * WIN);
    int oA = rA * WIN, oB = rB * WIN;
    uint32_t word = 0;
    for (int ci = 0; ci < CIN; ++ci) {
        const float* xc = xp + (size_t)ci * (DD * HIN * WIN);
        float a0 = xc[oA + cA], a1 = xc[oA + cB];
        float b0 = xc[oB + cA], b1 = xc[oB + cB];
        double t0 = wA * (double)a0 + wB * (double)b0;
        double t1 = wA * (double)a1 + wB * (double)b1;
        double v  = wC * t0 + wD * t1;
        word |= (v >= 0.0 ? 1u : 0u) << ci;
    }
    return word;
}

// ---------------------------------------------------------------------------
// packq: one thread packs a 2x2 output quad (h2=2m..2m+1, w2=2n..2n+1) from
// a 3x3 input neighborhood per channel. fp32 interpolation with fp64
// fallback when |v| < 1e-5 (fp32 abs err <= ~6e-7 on O(1) data).
// ---------------------------------------------------------------------------
__global__ __launch_bounds__(256) void ibc3d_packq(
    const float* __restrict__ x, uint32_t* __restrict__ bx,
    int b_start, int nplanes)
{
    int idx = blockIdx.x * 256 + threadIdx.x;   // [0, nplanes*8192)
    int n  = idx & (WIN - 1);        // w-pair index [0,128)
    int m  = (idx >> 7) & (HIN - 1); // h-pair index [0,64)
    int pl = idx >> 13;              // local plane
    if (pl >= nplanes) return;
    int d  = pl % DD;
    int b  = b_start + pl / DD;

    int rm1 = m > 0 ? m - 1 : 0;
    int rp1 = m < HIN - 1 ? m + 1 : HIN - 1;
    int cm1 = n > 0 ? n - 1 : 0;
    int cp1 = n < WIN - 1 ? n + 1 : WIN - 1;

    const float* xp = x + ((size_t)b * CIN * DD + d) * (HIN * WIN);
    int o0 = rm1 * WIN, o1 = m * WIN, o2 = rp1 * WIN;

    uint32_t w00 = 0, w01 = 0, w10 = 0, w11 = 0;
#pragma unroll 4
    for (int ci = 0; ci < CIN; ++ci) {
        const float* xc = xp + (size_t)ci * (DD * HIN * WIN);
        float a00 = xc[o0 + cm1], a01 = xc[o0 + n], a02 = xc[o0 + cp1];
        float a10 = xc[o1 + cm1], a11 = xc[o1 + n], a12 = xc[o1 + cp1];
        float a20 = xc[o2 + cm1], a21 = xc[o2 + n], a22 = xc[o2 + cp1];

        float u0r0 = 0.25f * a00 + 0.75f * a01, u1r0 = 0.75f * a01 + 0.25f * a02;
        float u0r1 = 0.25f * a10 + 0.75f * a11, u1r1 = 0.75f * a11 + 0.25f * a12;
        float u0r2 = 0.25f * a20 + 0.75f * a21, u1r2 = 0.75f * a21 + 0.25f * a22;

        float v00 = 0.25f * u0r0 + 0.75f * u0r1;
        float v01 = 0.25f * u1r0 + 0.75f * u1r1;
        float v10 = 0.75f * u0r1 + 0.25f * u0r2;
        float v11 = 0.75f * u1r1 + 0.25f * u1r2;

        uint32_t s00, s01, s10, s11;
        float amin = fminf(fminf(fabsf(v00), fabsf(v01)),
                           fminf(fabsf(v10), fabsf(v11)));
        if (__builtin_expect(amin < 1e-5f, 0)) {
            double d00 = a00, d01 = a01, d02 = a02;
            double d10 = a10, d11 = a11, d12 = a12;
            double d20 = a20, d21 = a21, d22 = a22;
            double e0r0 = 0.25 * d00 + 0.75 * d01, e1r0 = 0.75 * d01 + 0.25 * d02;
            double e0r1 = 0.25 * d10 + 0.75 * d11, e1r1 = 0.75 * d11 + 0.25 * d12;
            double e0r2 = 0.25 * d20 + 0.75 * d21, e1r2 = 0.75 * d21 + 0.25 * d22;
            s00 = (0.25 * e0r0 + 0.75 * e0r1) >= 0.0;
            s01 = (0.25 * e1r0 + 0.75 * e1r1) >= 0.0;
            s10 = (0.75 * e0r1 + 0.25 * e0r2) >= 0.0;
            s11 = (0.75 * e1r1 + 0.25 * e1r2) >= 0.0;
        } else {
            s00 = v00 >= 0.0f;
            s01 = v01 >= 0.0f;
            s10 = v10 >= 0.0f;
            s11 = v11 >= 0.0f;
        }
        w00 |= s00 << ci; w01 |= s01 << ci;
        w10 |= s10 << ci; w11 |= s11 << ci;
    }

    size_t base = (size_t)pl * PLANE_WORDS + (size_t)(2 * m) * W2 + 2 * n;
    *(uint2*)(bx + base)      = make_uint2(w00, w01);
    *(uint2*)(bx + base + W2) = make_uint2(w10, w11);
}

// ---------------------------------------------------------------------------
// conv3: one thread = one (plane, h2, w2), all 16 co. Weight words read with
// wave-uniform indices straight from global (-> scalar loads via K$), so the
// inner loop is pure v_xor + v_bcnt accumulate. nv computed arithmetically.
// ---------------------------------------------------------------------------
__global__ __launch_bounds__(256) void ibc3d_conv3(
    const uint32_t* __restrict__ bx, const uint32_t* __restrict__ bwg,
    const float* __restrict__ scaleg, const float* __restrict__ shiftg,
    float* __restrict__ out, int b_start)
{
    int bid   = blockIdx.x;          // plane*128 + h2
    int h2    = bid & (H2 - 1);
    int plane = bid >> 7;            // local plane [0, nplanes)
    int d     = plane % DD;
    int b     = b_start + plane / DD;
    int w2    = threadIdx.x;

    int acc[16];
#pragma unroll
    for (int c = 0; c < 16; ++c) acc[c] = 0;

#pragma unroll
    for (int kd = 0; kd < 3; ++kd) {
        int dd = d + kd - 1;
        if (dd < 0 || dd >= DD) continue;                 // wave-uniform
        const uint32_t* bxp = bx + (size_t)(plane + kd - 1) * PLANE_WORDS;
#pragma unroll
        for (int kh = 0; kh < 3; ++kh) {
            int hh = h2 + kh - 1;
            if (hh < 0 || hh >= H2) continue;             // wave-uniform
            const uint32_t* brow = bxp + hh * W2;
#pragma unroll
            for (int kw = 0; kw < 3; ++kw) {
                int ww = w2 + kw - 1;
                if (ww >= 0 && ww < W2) {                 // per-lane (edges only)
                    uint32_t word = brow[ww];
                    int tap = kd * 9 + kh * 3 + kw;
#pragma unroll
                    for (int co = 0; co < 16; ++co)
                        acc[co] += __popc(word ^ bwg[tap * 16 + co]);
                }
            }
        }
    }

    int nd = 1 + (d > 0)  + (d < DD - 1);
    int nh = 1 + (h2 > 0) + (h2 < H2 - 1);
    int nw = 1 + (w2 > 0) + (w2 < W2 - 1);
    float base = 32.0f * (float)(nd * nh * nw);

    size_t obase = (((size_t)(b * COUT) * DD + d) * H2 + h2) * W2 + w2;
#pragma unroll
    for (int co = 0; co < 16; ++co) {
        float y = (base - 2.0f * (float)acc[co]) * scaleg[co] + shiftg[co];
        y = y > 0.0f ? y : 0.0f;
        out[obase + (size_t)co * (DD * H2 * W2)] = y;
    }
}

// ---------------------------------------------------------------------------
// fused: zero-scratch fallback (unchanged structure from passing round).
// ---------------------------------------------------------------------------
__global__ __launch_bounds__(256) void ibc3d_fused(
    const float* __restrict__ x, const float* __restrict__ wgt,
    const float* __restrict__ gamma, const float* __restrict__ beta,
    const float* __restrict__ rmean, const float* __restrict__ rvar,
    float* __restrict__ out)
{
    __shared__ uint32_t sbw[27 * 16];
    __shared__ float sscale[16];
    __shared__ float sshift[16];
    __shared__ uint32_t sw[3][10][264];

    int tid = threadIdx.x;
    for (int t = tid; t < 27 * 16; t += 256) {
        int tap = t >> 4, co = t & 15;
        uint32_t word = 0;
        for (int ci = 0; ci < CIN; ++ci) {
            float v = wgt[(co * CIN + ci) * 27 + tap];
            word |= (v > 0.0f ? 1u : 0u) << ci;
        }
        sbw[t] = word;
    }
    if (tid < 16) {
        int co = tid;
        double s = 0.0;
        for (int i = 0; i < CIN * 27; ++i)
            s += fabs((double)wgt[co * CIN * 27 + i]);
        float alpha = (float)(s / (double)(CIN * 27));
        float inv = gamma[co] / sqrtf(rvar[co] + 1e-5f);
        sscale[co] = alpha * inv;
        sshift[co] = beta[co] - rmean[co] * inv;
    }

    int bid = blockIdx.x;
    int hq  = bid & 15;
    int r   = bid >> 4;
    int b   = r / DD;
    int d   = r % DD;
    int h2base = hq * 8;

    for (int i = tid; i < 3 * 10 * 258; i += 256) {
        int kd  = i / 2580;
        int rem = i - kd * 2580;
        int ri  = rem / 258;
        int ciw = rem - ri * 258;
        int dd = d + kd - 1;
        int h2 = h2base - 1 + ri;
        int w2 = ciw - 1;
        uint32_t word = 0;
        if (dd >= 0 && dd < DD && h2 >= 0 && h2 < H2 && w2 >= 0 && w2 < W2)
            word = pack_word(x, b, dd, h2, w2);
        sw[kd][ri][ciw] = word;
    }
    __syncthreads();

    int w2 = tid;
    for (int p = 0; p < 8; ++p) {
        int h2 = h2base + p;
        int acc[16];
#pragma unroll
        for (int c = 0; c < 16; ++c) acc[c] = 0;
        int nv = 0;
        for (int kd = 0; kd < 3; ++kd) {
            int dd = d + kd - 1;
            if (dd < 0 || dd >= DD) continue;
            for (int kh = 0; kh < 3; ++kh) {
                int hh = h2 + kh - 1;
                if (hh < 0 || hh >= H2) continue;
                for (int kw = 0; kw < 3; ++kw) {
                    int ww = w2 + kw - 1;
                    if (ww < 0 || ww >= W2) continue;
                    uint32_t word = sw[kd][p + kh][w2 + kw];
                    nv += 1;
                    int tap = kd * 9 + kh * 3 + kw;
#pragma unroll
                    for (int co = 0; co < 16; ++co)
                        acc[co] += __popc(word ^ sbw[tap * 16 + co]);
                }
            }
        }
        float base = 32.0f * (float)nv;
#pragma unroll
        for (int co = 0; co < 16; ++co) {
            float y = (base - 2.0f * (float)acc[co]) * sscale[co] + sshift[co];
            y = y > 0.0f ? y : 0.0f;
            size_t oidx = (((size_t)(b * COUT + co) * DD + d) * H2 + h2) * W2 + w2;
            out[oidx] = y;
        }
    }
}

extern "C" void kernel_launch(void* const* d_in, const int* in_sizes, int n_in,
                              void* d_out, int out_size, void* d_ws, size_t ws_size,
                              hipStream_t stream)
{
    (void)in_sizes; (void)n_in; (void)out_size;
    const float* x     = (const float*)d_in[0];
    const float* wgt   = (const float*)d_in[1];
    const float* gamma = (const float*)d_in[2];
    const float* beta  = (const float*)d_in[3];
    const float* rmean = (const float*)d_in[4];
    const float* rvar  = (const float*)d_in[5];
    float* out = (float*)d_out;

    const size_t HDR = 4096;
    const size_t bx_full = (size_t)BB * DD * PLANE_WORDS * 4;  // 12.58 MB
    const size_t bx_half = (size_t)DD * PLANE_WORDS * 4;       //  6.29 MB

    if (d_ws != nullptr && ws_size >= HDR + bx_full) {
        uint8_t* ws = (uint8_t*)d_ws;
        uint32_t* bw    = (uint32_t*)ws;
        float*    scale = (float*)(ws + 2048);
        float*    shift = (float*)(ws + 2112);
        uint32_t* bx    = (uint32_t*)(ws + HDR);
        ibc3d_prep<<<1, 512, 0, stream>>>(wgt, gamma, beta, rmean, rvar, bw, scale, shift);
        int nplanes = BB * DD;                      // 96
        ibc3d_packq<<<nplanes * 32, 256, 0, stream>>>(x, bx, 0, nplanes);
        ibc3d_conv3<<<nplanes * H2, 256, 0, stream>>>(bx, bw, scale, shift, out, 0);
    } else if (d_ws != nullptr && ws_size >= HDR + bx_half) {
        uint8_t* ws = (uint8_t*)d_ws;
        uint32_t* bw    = (uint32_t*)ws;
        float*    scale = (float*)(ws + 2048);
        float*    shift = (float*)(ws + 2112);
        uint32_t* bx    = (uint32_t*)(ws + HDR);
        ibc3d_prep<<<1, 512, 0, stream>>>(wgt, gamma, beta, rmean, rvar, bw, scale, shift);
        for (int b = 0; b < BB; ++b) {
            ibc3d_packq<<<DD * 32, 256, 0, stream>>>(x, bx, b, DD);
            ibc3d_conv3<<<DD * H2, 256, 0, stream>>>(bx, bw, scale, shift, out, b);
        }
    } else {
        ibc3d_fused<<<BB * DD * (H2 / 8), 256, 0, stream>>>(
            x, wgt, gamma, beta, rmean, rvar, out);
    }
}